// Round 10
// baseline (744.628 us; speedup 1.0000x reference)
//
#include <hip/hip_runtime.h>
#include <hip/hip_bf16.h>

#define T_SEQ   2048
#define D_MODEL 1024
#define N_HEADS 16
#define HEAD_DIM 64
#define BT      8192   // B*T
#define N3D     3072

using short8  = __attribute__((ext_vector_type(8))) short;
using short4v = __attribute__((ext_vector_type(4))) short;
using floatx4 = __attribute__((ext_vector_type(4))) float;

#define QSCALE 0.18033688f  // 0.125 * log2(e): folded into Q at QKV epilogue

__device__ __forceinline__ unsigned short rne_bf16(float f) {
  unsigned int u = __float_as_uint(f);
  u = (u + 0x7fffu + ((u >> 16) & 1u)) >> 16;
  return (unsigned short)u;
}

// async global->LDS, 16B per lane; dest = wave-uniform base + lane*16 (m104)
__device__ __forceinline__ void gload_lds16(const unsigned short* g,
                                            unsigned short* l) {
  __builtin_amdgcn_global_load_lds(
      (const __attribute__((address_space(1))) void*)g,
      (__attribute__((address_space(3))) void*)l, 16, 0, 0);
}

// ================= fused prep: convert + 2 weight transposes ==============
__device__ __forceinline__ void transpose_tile(const float* __restrict__ in,
                                               unsigned short* __restrict__ out_hi,
                                               int R, int C, int bid) {
  __shared__ float tile[64][65];
  int tiles_c = C >> 6;
  int r0 = (bid / tiles_c) << 6;
  int c0 = (bid % tiles_c) << 6;
  int tid = threadIdx.x;
#pragma unroll
  for (int i = 0; i < 16; ++i) {
    int idx = tid + i * 256;
    int r = idx >> 6, c = idx & 63;
    tile[r][c] = in[(size_t)(r0 + r) * C + c0 + c];
  }
  __syncthreads();
#pragma unroll
  for (int i = 0; i < 16; ++i) {
    int idx = tid + i * 256;
    int orow = idx >> 6, oc = idx & 63;
    out_hi[(size_t)(c0 + orow) * R + r0 + oc] = rne_bf16(tile[oc][orow]);
  }
}

__global__ __launch_bounds__(256) void k_prep(
    const float* __restrict__ x, unsigned short* __restrict__ x_bf,
    const float* __restrict__ wqkv, unsigned short* __restrict__ wq_T,
    const float* __restrict__ wproj, unsigned short* __restrict__ wp_T) {
  int bid = blockIdx.x;
  if (bid < 4096) {                      // convert x: 4096 blocks
    size_t i = ((size_t)bid * 256 + threadIdx.x) * 8;
    float4 a = *(const float4*)(x + i);
    float4 b = *(const float4*)(x + i + 4);
    short8 v;
    v[0] = (short)rne_bf16(a.x); v[1] = (short)rne_bf16(a.y);
    v[2] = (short)rne_bf16(a.z); v[3] = (short)rne_bf16(a.w);
    v[4] = (short)rne_bf16(b.x); v[5] = (short)rne_bf16(b.y);
    v[6] = (short)rne_bf16(b.z); v[7] = (short)rne_bf16(b.w);
    *(short8*)(((short*)x_bf) + i) = v;
  } else if (bid < 4096 + 768) {         // transpose wqkv: 16*48 = 768 blocks
    transpose_tile(wqkv, wq_T, 1024, 3072, bid - 4096);
  } else {                               // transpose wproj: 16*16 = 256 blocks
    transpose_tile(wproj, wp_T, 1024, 1024, bid - 4096 - 768);
  }
}

// ---------------- QKV GEMM (bf16 MFMA, BK=64, per-block orientation) ------
// R14/R5 structure (best measured). 128x128 tile, BK=64, 2-barrier K-loop,
// XOR-group LDS swizzle (0 conflicts), XCD-chunked grid, per-block mfma
// orientation: Q/K transposed (hd in register dir) for vectorized stores.
__global__ __launch_bounds__(256) void k_qkv_gemm(
    const unsigned short* __restrict__ A, const unsigned short* __restrict__ Bt,
    const float* __restrict__ bias,
    unsigned short* __restrict__ Qo, unsigned short* __restrict__ Ko,
    unsigned short* __restrict__ Vt) {
  __shared__ __align__(16) unsigned short As[128 * 64];
  __shared__ __align__(16) unsigned short Bs[128 * 64];
  int tid = threadIdx.x;
  int wg = (blockIdx.x & 7) * 192 + (blockIdx.x >> 3);  // XCD-chunked, bijective
  int m0 = (wg / 24) * 128;
  int n0 = (wg % 24) * 128;
  int which = n0 >> 10;            // block-uniform: 0=Q 1=K 2=V
  int w = tid >> 6, lane = tid & 63, quad = lane >> 4, l16 = lane & 15;
  int wm = (w >> 1) * 64, wn = (w & 1) * 64;
  floatx4 acc[4][4] = {};

  int r0 = tid >> 3;
  int gsh = (((tid & 7) ^ (r0 & 7)) << 3);   // shorts offset of logical group

  int a_off[4][2], b_off[4][2];
#pragma unroll
  for (int t = 0; t < 4; ++t) {
    int ra = wm + t * 16 + l16, rb = wn + t * 16 + l16;
#pragma unroll
    for (int ks = 0; ks < 2; ++ks) {
      a_off[t][ks] = ra * 64 + (((ks * 4 + quad) ^ (ra & 7)) << 3);
      b_off[t][ks] = rb * 64 + (((ks * 4 + quad) ^ (rb & 7)) << 3);
    }
  }

  for (int k0 = 0; k0 < 1024; k0 += 64) {
#pragma unroll
    for (int i = 0; i < 4; ++i) {
      int sub = (tid & ~63) + i * 256;
      gload_lds16(A + (size_t)(m0 + r0 + i * 32) * 1024 + k0 + gsh,
                  &As[sub * 8]);
      gload_lds16(Bt + (size_t)(n0 + r0 + i * 32) * 1024 + k0 + gsh,
                  &Bs[sub * 8]);
    }
    __syncthreads();
#pragma unroll
    for (int ks = 0; ks < 2; ++ks) {
      short8 af[4], bfr[4];
#pragma unroll
      for (int mt = 0; mt < 4; ++mt) af[mt] = *(const short8*)(&As[a_off[mt][ks]]);
#pragma unroll
      for (int nt = 0; nt < 4; ++nt) bfr[nt] = *(const short8*)(&Bs[b_off[nt][ks]]);
      if (which == 2) {
#pragma unroll
        for (int mt = 0; mt < 4; ++mt)
#pragma unroll
          for (int nt = 0; nt < 4; ++nt)
            acc[mt][nt] = __builtin_amdgcn_mfma_f32_16x16x32_bf16(af[mt], bfr[nt],
                                                                  acc[mt][nt], 0, 0, 0);
      } else {
#pragma unroll
        for (int mt = 0; mt < 4; ++mt)
#pragma unroll
          for (int nt = 0; nt < 4; ++nt)
            acc[mt][nt] = __builtin_amdgcn_mfma_f32_16x16x32_bf16(bfr[nt], af[mt],
                                                                  acc[mt][nt], 0, 0, 0);
      }
    }
    __syncthreads();
  }

  if (which == 2) {
#pragma unroll
    for (int nt = 0; nt < 4; ++nt) {
      int n = n0 + wn + nt * 16 + l16;
      float bv = bias[n];
      int nn = n & 1023;
      int h = nn >> 6, hd = nn & 63;
#pragma unroll
      for (int mt = 0; mt < 4; ++mt) {
        int mbase = m0 + wm + mt * 16 + quad * 4;
        int b = mbase >> 11;
        int t0 = mbase & 2047;
        int head = b * N_HEADS + h;
        short4v vv;
#pragma unroll
        for (int r = 0; r < 4; ++r) vv[r] = (short)rne_bf16(acc[mt][nt][r] + bv);
        *(short4v*)(&Vt[((size_t)head * HEAD_DIM + hd) * T_SEQ + t0]) = vv;
      }
    }
  } else {
    unsigned short* dst = (which == 0) ? Qo : Ko;
    float scl = (which == 0) ? QSCALE : 1.0f;
#pragma unroll
    for (int nt = 0; nt < 4; ++nt) {
      int nbase = n0 + wn + nt * 16 + quad * 4;
      int nn = nbase & 1023;
      int h = nn >> 6, hd0 = nn & 63;
      float4 bv4 = *(const float4*)(&bias[nbase]);
#pragma unroll
      for (int mt = 0; mt < 4; ++mt) {
        int m = m0 + wm + mt * 16 + l16;
        int b = m >> 11;
        int t = m & 2047;
        int head = b * N_HEADS + h;
        short4v ov;
        ov[0] = (short)rne_bf16((acc[mt][nt][0] + bv4.x) * scl);
        ov[1] = (short)rne_bf16((acc[mt][nt][1] + bv4.y) * scl);
        ov[2] = (short)rne_bf16((acc[mt][nt][2] + bv4.z) * scl);
        ov[3] = (short)rne_bf16((acc[mt][nt][3] + bv4.w) * scl);
        *(short4v*)(&dst[((size_t)head * T_SEQ + t) * HEAD_DIM + hd0]) = ov;
      }
    }
  }
}

// ---------------- flash attention: split-KV, 16 waves, in-LDS combine -----
// R17: softmax here has NO running max (pure exp2 accumulation), so partial
// attention over disjoint key ranges is exactly additive: O = O_A + O_B,
// l = l_A + l_B. Split the 32 KV-tiles across two 8-wave halves of ONE
// 1024-thread block. Each half runs the R10 pipeline BYTE-IDENTICAL in the
// loop (half folds into Kh/Vh/LDS base pointers at init -> zero extra live
// loop state -> VGPR stays at the proven 64; R8's spill lesson). LDS: 2
// halves x (K dbuf 2x8KB + V tri 3x8KB) = 80KB -> 2 blocks/CU = 32
// waves/CU (2x R10's residency; attacks the no-pipe-saturated latency
// plateau: MfmaUtil 34 / VALU 48 / Occ 36). Epilogue: half-1 writes fp32
// O (64KB) + Osum to the dead LDS, barrier, half-0 adds + normalizes by
// 1/(l_A+l_B), stores. Per-wave serial tiles 32 -> 16.
__global__ __launch_bounds__(1024, 8) void k_attn(
    const unsigned short* __restrict__ Q, const unsigned short* __restrict__ K,
    const unsigned short* __restrict__ Vt, unsigned short* __restrict__ Oo) {
  __shared__ __align__(16) unsigned short smemAll[40960];   // 80 KB
  int tid = threadIdx.x;
  int half = tid >> 9;                    // 0: KV[0:1024], 1: KV[1024:2048]
  int htid = tid & 511;
  int head = ((blockIdx.x & 7) << 3) + (blockIdx.x >> 6);  // XCD-grouped
  int qb = ((blockIdx.x >> 3) & 7) << 8;                   // 256 rows/block
  int b = head >> 4, h = head & 15;
  int wq = (tid >> 6) & 7, lane = tid & 63, quad = lane >> 4, l16 = lane & 15;
  const unsigned short* Qh = Q + (size_t)head * T_SEQ * HEAD_DIM;
  // fold the half's KV base into the global pointers (loop stays 0-based)
  const unsigned short* Kh = K + (size_t)head * T_SEQ * HEAD_DIM
                               + (size_t)(half * 1024) * HEAD_DIM;
  const unsigned short* Vh = Vt + (size_t)head * HEAD_DIM * T_SEQ
                               + half * 1024;

  short8 qf[2][2];
#pragma unroll
  for (int qi = 0; qi < 2; ++qi) {
    int qrow = qb + wq * 32 + qi * 16 + l16;
#pragma unroll
    for (int ks = 0; ks < 2; ++ks)
      qf[qi][ks] = *(const short8*)(Qh + (size_t)qrow * 64 + ks * 32 + quad * 8);
  }

  short8 ones;
#pragma unroll
  for (int j = 0; j < 8; ++j) ones[j] = (short)0x3F80;  // bf16 1.0

  floatx4 O[2][4] = {};
  floatx4 Osum[2] = {};
  const floatx4 zf = {};

  int sg = htid >> 6;                    // wave-uniform within half, 0..7
  int xs = lane ^ sg;
  int ntp = xs >> 4, mp = xs & 15;
  int ksrc = ((ntp >> 1) << 5) + ((mp >> 2) << 3) + ((ntp & 1) << 2) + (mp & 3);
  int vsrc = xs;
  int sub = htid & ~63;

  int pu[2][4];
#pragma unroll
  for (int ks = 0; ks < 2; ++ks) {
    int gk = ks * 4 + quad;
#pragma unroll
    for (int t = 0; t < 4; ++t)
      pu[ks][t] = (((gk << 6) + t * 16 + l16) ^ gk) << 3;
  }

  auto stageK = [&](unsigned short* dst, int kb) {
    gload_lds16(Kh + ((size_t)(kb * 64 + ksrc)) * 64 + sg * 8, dst + sub * 8);
  };
  auto stageV = [&](unsigned short* dst, int kb) {
    gload_lds16(Vh + (size_t)vsrc * T_SEQ + kb * 64 + sg * 8, dst + sub * 8);
  };

  short8 pPrev[2][2];

  auto qk = [&](const unsigned short* Kb_, floatx4 (&s)[2][4]) {
#pragma unroll
    for (int ks = 0; ks < 2; ++ks) {
#pragma unroll
      for (int nt = 0; nt < 4; ++nt) {
        short8 kf = *(const short8*)(Kb_ + pu[ks][nt]);
        if (ks == 0) {
          s[0][nt] = __builtin_amdgcn_mfma_f32_16x16x32_bf16(kf, qf[0][0], zf, 0, 0, 0);
          s[1][nt] = __builtin_amdgcn_mfma_f32_16x16x32_bf16(kf, qf[1][0], zf, 0, 0, 0);
        } else {
          s[0][nt] = __builtin_amdgcn_mfma_f32_16x16x32_bf16(kf, qf[0][1], s[0][nt], 0, 0, 0);
          s[1][nt] = __builtin_amdgcn_mfma_f32_16x16x32_bf16(kf, qf[1][1], s[1][nt], 0, 0, 0);
        }
      }
    }
  };

  auto pv = [&](const unsigned short* Vb_) {
#pragma unroll
    for (int ks = 0; ks < 2; ++ks) {
      Osum[0] = __builtin_amdgcn_mfma_f32_16x16x32_bf16(ones, pPrev[0][ks], Osum[0], 0, 0, 0);
      Osum[1] = __builtin_amdgcn_mfma_f32_16x16x32_bf16(ones, pPrev[1][ks], Osum[1], 0, 0, 0);
#pragma unroll
      for (int dt = 0; dt < 4; ++dt) {
        short8 vf = *(const short8*)(Vb_ + pu[ks][dt]);
        O[0][dt] = __builtin_amdgcn_mfma_f32_16x16x32_bf16(vf, pPrev[0][ks], O[0][dt], 0, 0, 0);
        O[1][dt] = __builtin_amdgcn_mfma_f32_16x16x32_bf16(vf, pPrev[1][ks], O[1][dt], 0, 0, 0);
      }
    }
  };

  auto expPack = [&](floatx4 (&s)[2][4]) {
#pragma unroll
    for (int qi = 0; qi < 2; ++qi) {
      unsigned int dw[4][2];
#pragma unroll
      for (int nt = 0; nt < 4; ++nt) {
        float p0 = __builtin_amdgcn_exp2f(s[qi][nt][0]);
        float p1 = __builtin_amdgcn_exp2f(s[qi][nt][1]);
        float p2 = __builtin_amdgcn_exp2f(s[qi][nt][2]);
        float p3 = __builtin_amdgcn_exp2f(s[qi][nt][3]);
        __hip_bfloat162 lo2 = __float22bfloat162_rn(make_float2(p0, p1));
        __hip_bfloat162 hi2 = __float22bfloat162_rn(make_float2(p2, p3));
        dw[nt][0] = *(unsigned int*)&lo2;
        dw[nt][1] = *(unsigned int*)&hi2;
      }
#pragma unroll
      for (int ks = 0; ks < 2; ++ks) {
        union { unsigned int u[4]; short8 s8; } cv;
        cv.u[0] = dw[2 * ks][0];
        cv.u[1] = dw[2 * ks][1];
        cv.u[2] = dw[2 * ks + 1][0];
        cv.u[3] = dw[2 * ks + 1][1];
        pPrev[qi][ks] = cv.s8;
      }
    }
  };

  // per-half LDS: base + {K: 0,1} x 4096, {V: 2,3,4} x 4096 (shorts)
  unsigned short* hbase = smemAll + half * 20480;
  unsigned short* Kcur = hbase + 4096;
  unsigned short* Koth = hbase;
  unsigned short* Vp = hbase + 8192;
  unsigned short* Vc = hbase + 12288;
  unsigned short* Vn = hbase + 16384;

  stageK(Koth, 0); stageV(Vp, 0);
  __syncthreads();
  stageK(Kcur, 1); stageV(Vc, 1);
  {
    floatx4 s[2][4];
    qk(Koth, s);
    expPack(s);
  }
  __syncthreads();

#pragma unroll 1
  for (int t = 1; t < 16; ++t) {
    if (t < 15) { stageK(Koth, t + 1); stageV(Vn, t + 1); }
    floatx4 s[2][4];
    __builtin_amdgcn_s_setprio(1);
    qk(Kcur, s);
    pv(Vp);
    __builtin_amdgcn_s_setprio(0);
    expPack(s);
    __syncthreads();
    unsigned short* tk = Kcur; Kcur = Koth; Koth = tk;
    unsigned short* tv = Vp; Vp = Vc; Vc = Vn; Vn = tv;
  }
  pv(Vp);                                 // PV(local tile 15)

  // -------- combine halves through LDS (both halves' loop reads done) ----
  __syncthreads();
  float* cO = (float*)smemAll;            // 512 thr x 32 f32 = 64 KB
  float* cS = cO + 16384;                 // 512 thr x 2 f32 = 4 KB
  if (half == 1) {
#pragma unroll
    for (int qi = 0; qi < 2; ++qi) {
      cS[htid * 2 + qi] = Osum[qi][0];
#pragma unroll
      for (int dt = 0; dt < 4; ++dt)
#pragma unroll
        for (int r = 0; r < 4; ++r)
          cO[htid * 32 + qi * 16 + dt * 4 + r] = O[qi][dt][r];
    }
  }
  __syncthreads();
  if (half == 0) {
#pragma unroll
    for (int qi = 0; qi < 2; ++qi) {
      float inv = 1.0f / (Osum[qi][0] + cS[htid * 2 + qi]);
      int t = qb + wq * 32 + qi * 16 + l16;
      size_t rowo = ((size_t)(b * T_SEQ + t)) * D_MODEL + h * HEAD_DIM;
#pragma unroll
      for (int dt = 0; dt < 4; ++dt) {
        short4v ov;
#pragma unroll
        for (int r = 0; r < 4; ++r)
          ov[r] = (short)rne_bf16(
              (O[qi][dt][r] + cO[htid * 32 + qi * 16 + dt * 4 + r]) * inv);
        *(short4v*)(&Oo[rowo + dt * 16 + quad * 4]) = ov;
      }
    }
  }
}

// ---------------- proj GEMM (bf16 MFMA, BK=64, R5 structure) --------------
// R14: transposed mfma orientation (rows=n in register dir) -> float4
// stores (16/thread) instead of 64 scalar dwords.
__global__ __launch_bounds__(256) void k_proj_gemm(
    const unsigned short* __restrict__ A, const unsigned short* __restrict__ Bt,
    const float* __restrict__ bias, float* __restrict__ out) {
  __shared__ __align__(16) unsigned short As[128 * 64];
  __shared__ __align__(16) unsigned short Bs[128 * 64];
  int tid = threadIdx.x;
  int wg = (blockIdx.x & 7) * 64 + (blockIdx.x >> 3);   // XCD-chunked, bijective
  int m0 = (wg >> 3) * 128;
  int n0 = (wg & 7) * 128;
  int w = tid >> 6, lane = tid & 63, quad = lane >> 4, l16 = lane & 15;
  int wm = (w >> 1) * 64, wn = (w & 1) * 64;
  floatx4 acc[4][4] = {};

  int r0 = tid >> 3;
  int gsh = (((tid & 7) ^ (r0 & 7)) << 3);

  int a_off[4][2], b_off[4][2];
#pragma unroll
  for (int t = 0; t < 4; ++t) {
    int ra = wm + t * 16 + l16, rb = wn + t * 16 + l16;
#pragma unroll
    for (int ks = 0; ks < 2; ++ks) {
      a_off[t][ks] = ra * 64 + (((ks * 4 + quad) ^ (ra & 7)) << 3);
      b_off[t][ks] = rb * 64 + (((ks * 4 + quad) ^ (rb & 7)) << 3);
    }
  }

  for (int k0 = 0; k0 < 1024; k0 += 64) {
#pragma unroll
    for (int i = 0; i < 4; ++i) {
      int sub = (tid & ~63) + i * 256;
      gload_lds16(A + (size_t)(m0 + r0 + i * 32) * 1024 + k0 + gsh,
                  &As[sub * 8]);
      gload_lds16(Bt + (size_t)(n0 + r0 + i * 32) * 1024 + k0 + gsh,
                  &Bs[sub * 8]);
    }
    __syncthreads();
#pragma unroll
    for (int ks = 0; ks < 2; ++ks) {
      short8 af[4], bfr[4];
#pragma unroll
      for (int mt = 0; mt < 4; ++mt) af[mt] = *(const short8*)(&As[a_off[mt][ks]]);
#pragma unroll
      for (int nt = 0; nt < 4; ++nt) bfr[nt] = *(const short8*)(&Bs[b_off[nt][ks]]);
#pragma unroll
      for (int mt = 0; mt < 4; ++mt)
#pragma unroll
        for (int nt = 0; nt < 4; ++nt)
          acc[mt][nt] = __builtin_amdgcn_mfma_f32_16x16x32_bf16(bfr[nt], af[mt],
                                                                acc[mt][nt], 0, 0, 0);
    }
    __syncthreads();
  }

#pragma unroll
  for (int nt = 0; nt < 4; ++nt) {
    int nbase = n0 + wn + nt * 16 + quad * 4;
    float4 bv4 = *(const float4*)(&bias[nbase]);
#pragma unroll
    for (int mt = 0; mt < 4; ++mt) {
      int m = m0 + wm + mt * 16 + l16;
      float4 o;
      o.x = acc[mt][nt][0] + bv4.x;
      o.y = acc[mt][nt][1] + bv4.y;
      o.z = acc[mt][nt][2] + bv4.z;
      o.w = acc[mt][nt][3] + bv4.w;
      *(float4*)(&out[(size_t)m * 1024 + nbase]) = o;
    }
  }
}

extern "C" void kernel_launch(void* const* d_in, const int* in_sizes, int n_in,
                              void* d_out, int out_size, void* d_ws, size_t ws_size,
                              hipStream_t stream) {
  const float* x     = (const float*)d_in[0];
  const float* wqkv  = (const float*)d_in[1];
  const float* bqkv  = (const float*)d_in[2];
  const float* wproj = (const float*)d_in[3];
  const float* bproj = (const float*)d_in[4];

  char* ws = (char*)d_ws;
  size_t off = 0;
  unsigned short* x_bf  = (unsigned short*)(ws + off); off += (size_t)BT * D_MODEL * 2;
  unsigned short* wq_T  = (unsigned short*)(ws + off); off += (size_t)N3D * D_MODEL * 2;
  unsigned short* wp_T  = (unsigned short*)(ws + off); off += (size_t)D_MODEL * D_MODEL * 2;
  unsigned short* Qb    = (unsigned short*)(ws + off); off += (size_t)BT * D_MODEL * 2;
  unsigned short* Kb    = (unsigned short*)(ws + off); off += (size_t)BT * D_MODEL * 2;
  unsigned short* Vt    = (unsigned short*)(ws + off); off += (size_t)BT * D_MODEL * 2;
  unsigned short* a_bf  = (unsigned short*)(ws + off); off += (size_t)BT * D_MODEL * 2;

  // fused prep: 4096 convert + 768 tr(wqkv) + 256 tr(wproj) = 5120 blocks
  k_prep<<<5120, 256, 0, stream>>>(x, x_bf, wqkv, wq_T, wproj, wp_T);
  k_qkv_gemm<<<(BT / 128) * (N3D / 128), 256, 0, stream>>>(x_bf, wq_T, bqkv, Qb, Kb, Vt);
  // 64 heads x 8 q-blocks = 512 blocks, 1024 threads (2 x 8-wave KV halves)
  k_attn<<<512, 1024, 0, stream>>>(Qb, Kb, Vt, a_bf);
  k_proj_gemm<<<(BT / 128) * (D_MODEL / 128), 256, 0, stream>>>(a_bf, wp_T, bproj, (float*)d_out);
}

// Round 11
// 271.590 us; speedup vs baseline: 2.7417x; 2.7417x over previous
//
#include <hip/hip_runtime.h>
#include <hip/hip_bf16.h>

#define T_SEQ   2048
#define D_MODEL 1024
#define N_HEADS 16
#define HEAD_DIM 64
#define BT      8192   // B*T
#define N3D     3072

using short8  = __attribute__((ext_vector_type(8))) short;
using short4v = __attribute__((ext_vector_type(4))) short;
using floatx4 = __attribute__((ext_vector_type(4))) float;

#define QSCALE 0.18033688f  // 0.125 * log2(e): folded into Q at QKV epilogue

__device__ __forceinline__ unsigned short rne_bf16(float f) {
  unsigned int u = __float_as_uint(f);
  u = (u + 0x7fffu + ((u >> 16) & 1u)) >> 16;
  return (unsigned short)u;
}

// async global->LDS, 16B per lane; dest = wave-uniform base + lane*16 (m104)
__device__ __forceinline__ void gload_lds16(const unsigned short* g,
                                            unsigned short* l) {
  __builtin_amdgcn_global_load_lds(
      (const __attribute__((address_space(1))) void*)g,
      (__attribute__((address_space(3))) void*)l, 16, 0, 0);
}

// ================= fused prep: convert + 2 weight transposes ==============
__device__ __forceinline__ void transpose_tile(const float* __restrict__ in,
                                               unsigned short* __restrict__ out_hi,
                                               int R, int C, int bid) {
  __shared__ float tile[64][65];
  int tiles_c = C >> 6;
  int r0 = (bid / tiles_c) << 6;
  int c0 = (bid % tiles_c) << 6;
  int tid = threadIdx.x;
#pragma unroll
  for (int i = 0; i < 16; ++i) {
    int idx = tid + i * 256;
    int r = idx >> 6, c = idx & 63;
    tile[r][c] = in[(size_t)(r0 + r) * C + c0 + c];
  }
  __syncthreads();
#pragma unroll
  for (int i = 0; i < 16; ++i) {
    int idx = tid + i * 256;
    int orow = idx >> 6, oc = idx & 63;
    out_hi[(size_t)(c0 + orow) * R + r0 + oc] = rne_bf16(tile[oc][orow]);
  }
}

__global__ __launch_bounds__(256) void k_prep(
    const float* __restrict__ x, unsigned short* __restrict__ x_bf,
    const float* __restrict__ wqkv, unsigned short* __restrict__ wq_T,
    const float* __restrict__ wproj, unsigned short* __restrict__ wp_T) {
  int bid = blockIdx.x;
  if (bid < 4096) {                      // convert x: 4096 blocks
    size_t i = ((size_t)bid * 256 + threadIdx.x) * 8;
    float4 a = *(const float4*)(x + i);
    float4 b = *(const float4*)(x + i + 4);
    short8 v;
    v[0] = (short)rne_bf16(a.x); v[1] = (short)rne_bf16(a.y);
    v[2] = (short)rne_bf16(a.z); v[3] = (short)rne_bf16(a.w);
    v[4] = (short)rne_bf16(b.x); v[5] = (short)rne_bf16(b.y);
    v[6] = (short)rne_bf16(b.z); v[7] = (short)rne_bf16(b.w);
    *(short8*)(((short*)x_bf) + i) = v;
  } else if (bid < 4096 + 768) {         // transpose wqkv: 16*48 = 768 blocks
    transpose_tile(wqkv, wq_T, 1024, 3072, bid - 4096);
  } else {                               // transpose wproj: 16*16 = 256 blocks
    transpose_tile(wproj, wp_T, 1024, 1024, bid - 4096 - 768);
  }
}

// ---------------- QKV GEMM (bf16 MFMA, BK=64, per-block orientation) ------
// R14/R5 structure (best measured). 128x128 tile, BK=64, 2-barrier K-loop,
// XOR-group LDS swizzle (0 conflicts), XCD-chunked grid, per-block mfma
// orientation: Q/K transposed (hd in register dir) for vectorized stores.
__global__ __launch_bounds__(256) void k_qkv_gemm(
    const unsigned short* __restrict__ A, const unsigned short* __restrict__ Bt,
    const float* __restrict__ bias,
    unsigned short* __restrict__ Qo, unsigned short* __restrict__ Ko,
    unsigned short* __restrict__ Vt) {
  __shared__ __align__(16) unsigned short As[128 * 64];
  __shared__ __align__(16) unsigned short Bs[128 * 64];
  int tid = threadIdx.x;
  int wg = (blockIdx.x & 7) * 192 + (blockIdx.x >> 3);  // XCD-chunked, bijective
  int m0 = (wg / 24) * 128;
  int n0 = (wg % 24) * 128;
  int which = n0 >> 10;            // block-uniform: 0=Q 1=K 2=V
  int w = tid >> 6, lane = tid & 63, quad = lane >> 4, l16 = lane & 15;
  int wm = (w >> 1) * 64, wn = (w & 1) * 64;
  floatx4 acc[4][4] = {};

  int r0 = tid >> 3;
  int gsh = (((tid & 7) ^ (r0 & 7)) << 3);   // shorts offset of logical group

  int a_off[4][2], b_off[4][2];
#pragma unroll
  for (int t = 0; t < 4; ++t) {
    int ra = wm + t * 16 + l16, rb = wn + t * 16 + l16;
#pragma unroll
    for (int ks = 0; ks < 2; ++ks) {
      a_off[t][ks] = ra * 64 + (((ks * 4 + quad) ^ (ra & 7)) << 3);
      b_off[t][ks] = rb * 64 + (((ks * 4 + quad) ^ (rb & 7)) << 3);
    }
  }

  for (int k0 = 0; k0 < 1024; k0 += 64) {
#pragma unroll
    for (int i = 0; i < 4; ++i) {
      int sub = (tid & ~63) + i * 256;
      gload_lds16(A + (size_t)(m0 + r0 + i * 32) * 1024 + k0 + gsh,
                  &As[sub * 8]);
      gload_lds16(Bt + (size_t)(n0 + r0 + i * 32) * 1024 + k0 + gsh,
                  &Bs[sub * 8]);
    }
    __syncthreads();
#pragma unroll
    for (int ks = 0; ks < 2; ++ks) {
      short8 af[4], bfr[4];
#pragma unroll
      for (int mt = 0; mt < 4; ++mt) af[mt] = *(const short8*)(&As[a_off[mt][ks]]);
#pragma unroll
      for (int nt = 0; nt < 4; ++nt) bfr[nt] = *(const short8*)(&Bs[b_off[nt][ks]]);
      if (which == 2) {
#pragma unroll
        for (int mt = 0; mt < 4; ++mt)
#pragma unroll
          for (int nt = 0; nt < 4; ++nt)
            acc[mt][nt] = __builtin_amdgcn_mfma_f32_16x16x32_bf16(af[mt], bfr[nt],
                                                                  acc[mt][nt], 0, 0, 0);
      } else {
#pragma unroll
        for (int mt = 0; mt < 4; ++mt)
#pragma unroll
          for (int nt = 0; nt < 4; ++nt)
            acc[mt][nt] = __builtin_amdgcn_mfma_f32_16x16x32_bf16(bfr[nt], af[mt],
                                                                  acc[mt][nt], 0, 0, 0);
      }
    }
    __syncthreads();
  }

  if (which == 2) {
#pragma unroll
    for (int nt = 0; nt < 4; ++nt) {
      int n = n0 + wn + nt * 16 + l16;
      float bv = bias[n];
      int nn = n & 1023;
      int h = nn >> 6, hd = nn & 63;
#pragma unroll
      for (int mt = 0; mt < 4; ++mt) {
        int mbase = m0 + wm + mt * 16 + quad * 4;
        int b = mbase >> 11;
        int t0 = mbase & 2047;
        int head = b * N_HEADS + h;
        short4v vv;
#pragma unroll
        for (int r = 0; r < 4; ++r) vv[r] = (short)rne_bf16(acc[mt][nt][r] + bv);
        *(short4v*)(&Vt[((size_t)head * HEAD_DIM + hd) * T_SEQ + t0]) = vv;
      }
    }
  } else {
    unsigned short* dst = (which == 0) ? Qo : Ko;
    float scl = (which == 0) ? QSCALE : 1.0f;
#pragma unroll
    for (int nt = 0; nt < 4; ++nt) {
      int nbase = n0 + wn + nt * 16 + quad * 4;
      int nn = nbase & 1023;
      int h = nn >> 6, hd0 = nn & 63;
      float4 bv4 = *(const float4*)(&bias[nbase]);
#pragma unroll
      for (int mt = 0; mt < 4; ++mt) {
        int m = m0 + wm + mt * 16 + l16;
        int b = m >> 11;
        int t = m & 2047;
        int head = b * N_HEADS + h;
        short4v ov;
        ov[0] = (short)rne_bf16((acc[mt][nt][0] + bv4.x) * scl);
        ov[1] = (short)rne_bf16((acc[mt][nt][1] + bv4.y) * scl);
        ov[2] = (short)rne_bf16((acc[mt][nt][2] + bv4.z) * scl);
        ov[3] = (short)rne_bf16((acc[mt][nt][3] + bv4.w) * scl);
        *(short4v*)(&dst[((size_t)head * T_SEQ + t) * HEAD_DIM + hd0]) = ov;
      }
    }
  }
}

// ---------------- flash attention (S^T form, T15 pipeline, QBLK=128) -------
// R18: the unconfounded occupancy experiment. R3 changed QBLK(128->256) AND
// XCD-grouping together; QBLK=128 + XCD-grouping + 8 waves was never
// tested. Per-wave q-rows halve (qi dimension removed): O[4], qf[2],
// pPrev[2], s[4] -> est ~50 VGPR (UNDER the proven-necessary 64; R15/R17
// died by demanding occupancy the allocator paid for with spills — this
// raises residency by SHRINKING state instead). Grid 512->1024 = 4
// blocks/CU x 8 waves = 32 waves/CU cap (2x R9; R9 was grid-limited at
// 50% cap, measured 36%). LDS 40KB x 4 = exactly 160KB. XCD map: all 16
// q-blocks of a head on one XCD -> extra KV re-reads are L2-hits.
// launch_bounds(512,4) only (a minimum, no allocator squeeze). Loop
// structure byte-identical to R9 per 64-key tile.
__global__ __launch_bounds__(512, 4) void k_attn(
    const unsigned short* __restrict__ Q, const unsigned short* __restrict__ K,
    const unsigned short* __restrict__ Vt, unsigned short* __restrict__ Oo) {
  __shared__ __align__(16) unsigned short Klds[2][64 * 64];
  __shared__ __align__(16) unsigned short Vlds[3][64 * 64];
  int tid = threadIdx.x;
  // 1024 blocks: xcd = blk&7, qidx = (blk>>3)&15, headhi = blk>>7
  int head = ((blockIdx.x & 7) << 3) + (blockIdx.x >> 7);  // XCD-grouped
  int qb = ((blockIdx.x >> 3) & 15) << 7;                  // 128 rows/block
  int b = head >> 4, h = head & 15;
  int w = tid >> 6, lane = tid & 63, quad = lane >> 4, l16 = lane & 15;
  const unsigned short* Qh = Q + (size_t)head * T_SEQ * HEAD_DIM;
  const unsigned short* Kh = K + (size_t)head * T_SEQ * HEAD_DIM;
  const unsigned short* Vh = Vt + (size_t)head * HEAD_DIM * T_SEQ;

  // Q B-frag: wave w owns rows qb + w*16 .. +15 (16 q-rows per wave)
  short8 qf[2];
  {
    int qrow = qb + w * 16 + l16;
#pragma unroll
    for (int ks = 0; ks < 2; ++ks)
      qf[ks] = *(const short8*)(Qh + (size_t)qrow * 64 + ks * 32 + quad * 8);
  }

  short8 ones;
#pragma unroll
  for (int j = 0; j < 8; ++j) ones[j] = (short)0x3F80;  // bf16 1.0

  floatx4 O[4] = {};
  floatx4 Osum = {};
  const floatx4 zf = {};

  int sg = tid >> 6;
  int xs = lane ^ sg;
  int ntp = xs >> 4, mp = xs & 15;
  int ksrc = ((ntp >> 1) << 5) + ((mp >> 2) << 3) + ((ntp & 1) << 2) + (mp & 3);
  int vsrc = xs;
  int sub = tid & ~63;

  int pu[2][4];
#pragma unroll
  for (int ks = 0; ks < 2; ++ks) {
    int gk = ks * 4 + quad;
#pragma unroll
    for (int t = 0; t < 4; ++t)
      pu[ks][t] = (((gk << 6) + t * 16 + l16) ^ gk) << 3;
  }

  auto stageK = [&](unsigned short* dst, int kb) {
    gload_lds16(Kh + ((size_t)(kb * 64 + ksrc)) * 64 + sg * 8, dst + sub * 8);
  };
  auto stageV = [&](unsigned short* dst, int kb) {
    gload_lds16(Vh + (size_t)vsrc * T_SEQ + kb * 64 + sg * 8, dst + sub * 8);
  };

  short8 pPrev[2];

  auto qk = [&](const unsigned short* Kb_, floatx4 (&s)[4]) {
#pragma unroll
    for (int ks = 0; ks < 2; ++ks) {
#pragma unroll
      for (int nt = 0; nt < 4; ++nt) {
        short8 kf = *(const short8*)(Kb_ + pu[ks][nt]);
        if (ks == 0)
          s[nt] = __builtin_amdgcn_mfma_f32_16x16x32_bf16(kf, qf[0], zf, 0, 0, 0);
        else
          s[nt] = __builtin_amdgcn_mfma_f32_16x16x32_bf16(kf, qf[1], s[nt], 0, 0, 0);
      }
    }
  };

  auto pv = [&](const unsigned short* Vb_) {
#pragma unroll
    for (int ks = 0; ks < 2; ++ks) {
      Osum = __builtin_amdgcn_mfma_f32_16x16x32_bf16(ones, pPrev[ks], Osum, 0, 0, 0);
#pragma unroll
      for (int dt = 0; dt < 4; ++dt) {
        short8 vf = *(const short8*)(Vb_ + pu[ks][dt]);
        O[dt] = __builtin_amdgcn_mfma_f32_16x16x32_bf16(vf, pPrev[ks], O[dt], 0, 0, 0);
      }
    }
  };

  auto expPack = [&](floatx4 (&s)[4]) {
    unsigned int dw[4][2];
#pragma unroll
    for (int nt = 0; nt < 4; ++nt) {
      float p0 = __builtin_amdgcn_exp2f(s[nt][0]);
      float p1 = __builtin_amdgcn_exp2f(s[nt][1]);
      float p2 = __builtin_amdgcn_exp2f(s[nt][2]);
      float p3 = __builtin_amdgcn_exp2f(s[nt][3]);
      __hip_bfloat162 lo2 = __float22bfloat162_rn(make_float2(p0, p1));
      __hip_bfloat162 hi2 = __float22bfloat162_rn(make_float2(p2, p3));
      dw[nt][0] = *(unsigned int*)&lo2;
      dw[nt][1] = *(unsigned int*)&hi2;
    }
#pragma unroll
    for (int ks = 0; ks < 2; ++ks) {
      union { unsigned int u[4]; short8 s8; } cv;
      cv.u[0] = dw[2 * ks][0];
      cv.u[1] = dw[2 * ks][1];
      cv.u[2] = dw[2 * ks + 1][0];
      cv.u[3] = dw[2 * ks + 1][1];
      pPrev[ks] = cv.s8;
    }
  };

  unsigned short* Kcur = &Klds[1][0];
  unsigned short* Koth = &Klds[0][0];
  unsigned short* Vp = &Vlds[0][0];
  unsigned short* Vc = &Vlds[1][0];
  unsigned short* Vn = &Vlds[2][0];

  stageK(Koth, 0); stageV(Vp, 0);
  __syncthreads();
  stageK(Kcur, 1); stageV(Vc, 1);
  {
    floatx4 s[4];
    qk(Koth, s);
    expPack(s);
  }
  __syncthreads();

#pragma unroll 1
  for (int t = 1; t < 32; ++t) {
    if (t < 31) { stageK(Koth, t + 1); stageV(Vn, t + 1); }
    floatx4 s[4];
    __builtin_amdgcn_s_setprio(1);
    qk(Kcur, s);
    pv(Vp);
    __builtin_amdgcn_s_setprio(0);
    expPack(s);
    __syncthreads();
    unsigned short* tk = Kcur; Kcur = Koth; Koth = tk;
    unsigned short* tv = Vp; Vp = Vc; Vc = Vn; Vn = tv;
  }
  pv(Vp);

  {
    float inv = 1.0f / Osum[0];
    int t = qb + w * 16 + l16;
    size_t rowo = ((size_t)(b * T_SEQ + t)) * D_MODEL + h * HEAD_DIM;
#pragma unroll
    for (int dt = 0; dt < 4; ++dt) {
      short4v ov;
#pragma unroll
      for (int r = 0; r < 4; ++r) ov[r] = (short)rne_bf16(O[dt][r] * inv);
      *(short4v*)(&Oo[rowo + dt * 16 + quad * 4]) = ov;
    }
  }
}

// ---------------- proj GEMM (bf16 MFMA, BK=64, R5 structure) --------------
// R14: transposed mfma orientation (rows=n in register dir) -> float4
// stores (16/thread) instead of 64 scalar dwords.
__global__ __launch_bounds__(256) void k_proj_gemm(
    const unsigned short* __restrict__ A, const unsigned short* __restrict__ Bt,
    const float* __restrict__ bias, float* __restrict__ out) {
  __shared__ __align__(16) unsigned short As[128 * 64];
  __shared__ __align__(16) unsigned short Bs[128 * 64];
  int tid = threadIdx.x;
  int wg = (blockIdx.x & 7) * 64 + (blockIdx.x >> 3);   // XCD-chunked, bijective
  int m0 = (wg >> 3) * 128;
  int n0 = (wg & 7) * 128;
  int w = tid >> 6, lane = tid & 63, quad = lane >> 4, l16 = lane & 15;
  int wm = (w >> 1) * 64, wn = (w & 1) * 64;
  floatx4 acc[4][4] = {};

  int r0 = tid >> 3;
  int gsh = (((tid & 7) ^ (r0 & 7)) << 3);

  int a_off[4][2], b_off[4][2];
#pragma unroll
  for (int t = 0; t < 4; ++t) {
    int ra = wm + t * 16 + l16, rb = wn + t * 16 + l16;
#pragma unroll
    for (int ks = 0; ks < 2; ++ks) {
      a_off[t][ks] = ra * 64 + (((ks * 4 + quad) ^ (ra & 7)) << 3);
      b_off[t][ks] = rb * 64 + (((ks * 4 + quad) ^ (rb & 7)) << 3);
    }
  }

  for (int k0 = 0; k0 < 1024; k0 += 64) {
#pragma unroll
    for (int i = 0; i < 4; ++i) {
      int sub = (tid & ~63) + i * 256;
      gload_lds16(A + (size_t)(m0 + r0 + i * 32) * 1024 + k0 + gsh,
                  &As[sub * 8]);
      gload_lds16(Bt + (size_t)(n0 + r0 + i * 32) * 1024 + k0 + gsh,
                  &Bs[sub * 8]);
    }
    __syncthreads();
#pragma unroll
    for (int ks = 0; ks < 2; ++ks) {
      short8 af[4], bfr[4];
#pragma unroll
      for (int mt = 0; mt < 4; ++mt) af[mt] = *(const short8*)(&As[a_off[mt][ks]]);
#pragma unroll
      for (int nt = 0; nt < 4; ++nt) bfr[nt] = *(const short8*)(&Bs[b_off[nt][ks]]);
#pragma unroll
      for (int mt = 0; mt < 4; ++mt)
#pragma unroll
        for (int nt = 0; nt < 4; ++nt)
          acc[mt][nt] = __builtin_amdgcn_mfma_f32_16x16x32_bf16(bfr[nt], af[mt],
                                                                acc[mt][nt], 0, 0, 0);
    }
    __syncthreads();
  }

#pragma unroll
  for (int nt = 0; nt < 4; ++nt) {
    int nbase = n0 + wn + nt * 16 + quad * 4;
    float4 bv4 = *(const float4*)(&bias[nbase]);
#pragma unroll
    for (int mt = 0; mt < 4; ++mt) {
      int m = m0 + wm + mt * 16 + l16;
      float4 o;
      o.x = acc[mt][nt][0] + bv4.x;
      o.y = acc[mt][nt][1] + bv4.y;
      o.z = acc[mt][nt][2] + bv4.z;
      o.w = acc[mt][nt][3] + bv4.w;
      *(float4*)(&out[(size_t)m * 1024 + nbase]) = o;
    }
  }
}

extern "C" void kernel_launch(void* const* d_in, const int* in_sizes, int n_in,
                              void* d_out, int out_size, void* d_ws, size_t ws_size,
                              hipStream_t stream) {
  const float* x     = (const float*)d_in[0];
  const float* wqkv  = (const float*)d_in[1];
  const float* bqkv  = (const float*)d_in[2];
  const float* wproj = (const float*)d_in[3];
  const float* bproj = (const float*)d_in[4];

  char* ws = (char*)d_ws;
  size_t off = 0;
  unsigned short* x_bf  = (unsigned short*)(ws + off); off += (size_t)BT * D_MODEL * 2;
  unsigned short* wq_T  = (unsigned short*)(ws + off); off += (size_t)N3D * D_MODEL * 2;
  unsigned short* wp_T  = (unsigned short*)(ws + off); off += (size_t)D_MODEL * D_MODEL * 2;
  unsigned short* Qb    = (unsigned short*)(ws + off); off += (size_t)BT * D_MODEL * 2;
  unsigned short* Kb    = (unsigned short*)(ws + off); off += (size_t)BT * D_MODEL * 2;
  unsigned short* Vt    = (unsigned short*)(ws + off); off += (size_t)BT * D_MODEL * 2;
  unsigned short* a_bf  = (unsigned short*)(ws + off); off += (size_t)BT * D_MODEL * 2;

  // fused prep: 4096 convert + 768 tr(wqkv) + 256 tr(wproj) = 5120 blocks
  k_prep<<<5120, 256, 0, stream>>>(x, x_bf, wqkv, wq_T, wproj, wp_T);
  k_qkv_gemm<<<(BT / 128) * (N3D / 128), 256, 0, stream>>>(x_bf, wq_T, bqkv, Qb, Kb, Vt);
  // 64 heads x (T/128)=16 q-blocks = 1024 blocks, 512 threads (8 waves)
  k_attn<<<1024, 512, 0, stream>>>(Qb, Kb, Vt, a_bf);
  k_proj_gemm<<<(BT / 128) * (D_MODEL / 128), 256, 0, stream>>>(a_bf, wp_T, bproj, (float*)d_out);
}